// Round 6
// baseline (210.007 us; speedup 1.0000x reference)
//
#include <hip/hip_runtime.h>
#include <stdint.h>

// Problem constants: N=128, T=2048, D=88
#define NN 128
#define TT 2048
#define DD 88
#define ROWS 32                            // timesteps per tile
#define TILES 4                            // tiles per block (grid-stride)
#define TILES_TOTAL (NN * TT / ROWS)       // 8192
#define K1_BLOCKS (TILES_TOTAL / TILES)    // 2048 longer-lived blocks
#define F4_TILE (ROWS * DD / 4)            // 704 float4 per array per tile
#define PARTS_PER_N (TT / (ROWS * TILES))  // 16 tp partials per n

typedef float f4 __attribute__((ext_vector_type(4)));
typedef const __attribute__((address_space(1))) uint32_t guint;
typedef __attribute__((address_space(3))) uint32_t luint;

// K1: async global->LDS staging; each block streams 4 consecutive 32-row
// tiles (all within one n since 64 tiles/n is divisible by 4) to keep CUs
// at steady-state wave count (fill the read fabric).
__global__ __launch_bounds__(256) void acc_rowstats_kernel(
    const float* __restrict__ outp, const float* __restrict__ tgt,
    float* __restrict__ fpfn, float* __restrict__ tp_part) {
  __shared__ f4 lds_o[F4_TILE];
  __shared__ f4 lds_g[F4_TILE];
  __shared__ float s_tp[4];

  const int tid = threadIdx.x;
  const int lane = tid & 63;
  const int wave = tid >> 6;
  const int blk = blockIdx.x;
  const int r = tid >> 3;  // row 0..31
  const int s = tid & 7;   // 8 threads per row

  float tp = 0.f;
  for (int t4 = 0; t4 < TILES; ++t4) {
    const int tile = blk * TILES + t4;
    const size_t tile_f = (size_t)tile * (ROWS * DD);

    // ---- stage 22 x 1KB direct-to-LDS (no VGPR round-trip) ----
    for (int j = wave; j < 22; j += 4) {
      const int is_g = (j >= 11) ? 1 : 0;
      const int idx = j - is_g * 11;  // wave-uniform
      const float* src = (is_g ? tgt : outp) + tile_f + idx * 256;
      float* dst = (is_g ? (float*)lds_g : (float*)lds_o) + idx * 256;
      __builtin_amdgcn_global_load_lds((guint*)src + lane * 4, (luint*)dst,
                                       16, 0, 0);
    }
    __syncthreads();  // drains vmcnt

    // ---- consume from LDS: 8 threads per row ----
    float x = 0.f;
#pragma unroll
    for (int j0 = 0; j0 < 3; ++j0) {
      const int j = s + j0 * 8;
      if (j < 22) {
        const f4 o = lds_o[r * 22 + j];
        const f4 g = lds_g[r * 22 + j];
        {
          const float pf = (o.x > 0.f) ? 1.f : 0.f;
          x += fabsf(pf - g.x);
          tp = fmaf(pf, g.x, tp);
        }
        {
          const float pf = (o.y > 0.f) ? 1.f : 0.f;
          x += fabsf(pf - g.y);
          tp = fmaf(pf, g.y, tp);
        }
        {
          const float pf = (o.z > 0.f) ? 1.f : 0.f;
          x += fabsf(pf - g.z);
          tp = fmaf(pf, g.z, tp);
        }
        {
          const float pf = (o.w > 0.f) ? 1.f : 0.f;
          x += fabsf(pf - g.w);
          tp = fmaf(pf, g.w, tp);
        }
      }
    }
    // per-row fpfn across the 8 contiguous lanes of this row
    x += __shfl_down(x, 4, 64);
    x += __shfl_down(x, 2, 64);
    x += __shfl_down(x, 1, 64);
    if (s == 0) fpfn[(size_t)tile * ROWS + r] = x;
    __syncthreads();  // protect LDS before restaging next tile
  }

  // ---- tp block-reduce -> deterministic per-block partial ----
  for (int off = 32; off > 0; off >>= 1) tp += __shfl_down(tp, off, 64);
  if (lane == 0) s_tp[wave] = tp;
  __syncthreads();
  if (tid == 0) tp_part[blk] = s_tp[0] + s_tp[1] + s_tp[2] + s_tp[3];
}

// K2: one block per n; acc[n] computed and atomicAdd'ed into out[0]
// (tail structure proven cost-neutral in R2 vs R4).
__global__ __launch_bounds__(256) void acc_finalize_kernel(
    const int* __restrict__ mask, const float* __restrict__ fpfn,
    const float* __restrict__ tp_part, float* __restrict__ out) {
  const int n = blockIdx.x;
  const int tid = threadIdx.x;
  __shared__ float sa[256], sb[256];

  // T_i via int4 loads (2048 ints = 512 int4)
  const int4* m4 = (const int4*)(mask + (size_t)n * TT);
  int ti = 0;
#pragma unroll
  for (int it = 0; it < 2; ++it) {
    const int4 v = m4[it * 256 + tid];
    ti += v.x + v.y + v.z + v.w;
  }
  const float tpv = (tid < PARTS_PER_N) ? tp_part[n * PARTS_PER_N + tid] : 0.f;

  sa[tid] = (float)ti;
  sb[tid] = tpv;
  __syncthreads();
  for (int s = 128; s > 0; s >>= 1) {
    if (tid < s) { sa[tid] += sa[tid + s]; sb[tid] += sb[tid + s]; }
    __syncthreads();
  }
  const float fTi = sa[0];
  const float tp = sb[0];
  const int Ti = (int)fTi;
  __syncthreads();

  const float* __restrict__ fr = fpfn + (size_t)n * TT;
  float a = 0.f;
  for (int t = tid; t < Ti; t += 256) a += tp / (tp + fr[t]);
  sa[tid] = a;
  __syncthreads();
  for (int s = 128; s > 0; s >>= 1) {
    if (tid < s) sa[tid] += sa[tid + s];
    __syncthreads();
  }
  if (tid == 0) atomicAdd(out, sa[0] / fTi);
}

extern "C" void kernel_launch(void* const* d_in, const int* in_sizes, int n_in,
                              void* d_out, int out_size, void* d_ws, size_t ws_size,
                              hipStream_t stream) {
  const float* output = (const float*)d_in[0];
  const float* target = (const float*)d_in[1];
  const int* mask = (const int*)d_in[2];
  float* out = (float*)d_out;

  float* tp_part = (float*)d_ws;          // K1_BLOCKS floats
  float* fpfn = tp_part + K1_BLOCKS;      // N*T floats

  hipMemsetAsync(d_out, 0, sizeof(float) * out_size, stream);
  acc_rowstats_kernel<<<K1_BLOCKS, 256, 0, stream>>>(output, target, fpfn, tp_part);
  acc_finalize_kernel<<<NN, 256, 0, stream>>>(mask, fpfn, tp_part, out);
}